// Round 3
// baseline (473.219 us; speedup 1.0000x reference)
//
#include <hip/hip_runtime.h>
#include <math.h>

#define DTC 0.01f
#define NZ 56      // 55 Z components + 1 zero pad
#define ZH 28      // z per staged half-tile
#define SSTR 260   // per-sample M stride in floats (256 + 4 pad for banks)

// ---------------- device scratch ----------------
__device__ float g_Wre[225*240];   // [ij][de]
__device__ float g_Wim[225*240];
__device__ float g_Pxx[15*225];
__device__ float g_Pyy[15*225];
__device__ float g_Cim[25*225];
__device__ float g_G  [NZ*256];    // [z][entry], entry slot-swizzled

__constant__ int c_pa[15] = {0,0,0,0,0,1,1,1,1,2,2,2,3,3,4};
__constant__ int c_pb[15] = {0,1,2,3,4,1,2,3,4,2,3,4,3,4,4};

#define QPERM(ctrl_, v_) __int_as_float(__builtin_amdgcn_update_dpp( \
    __float_as_int(v_), __float_as_int(v_), (ctrl_), 0xF, 0xF, true))

// ---------------------------------------------------------------------------
// PK1: per (i,j) block: W rows (structure-constant contractions) + P tensors
// ---------------------------------------------------------------------------
__global__ void pk1(const float* __restrict__ f, const float* __restrict__ d,
                    const float* __restrict__ wx4, const float* __restrict__ bx4,
                    const float* __restrict__ wy4, const float* __restrict__ by4)
{
  const int b = blockIdx.x;           // ij = i*15+j
  const int i = b / 15, j = b % 15;
  const int t = threadIdx.x;

  if (t < 240) {
    float wre = 0.f, wim = 0.f;
    if (t < 225) {
      const int al = t / 15, be = t % 15;
      float sre = 0.f, sim = 0.f;
      for (int k = 0; k < 15; ++k) {
        const float faj = f[(al*15 + j)*15 + k];
        const float fai = f[(al*15 + i)*15 + k];
        const float fbi = f[(be*15 + i)*15 + k];
        const float fbj = f[(be*15 + j)*15 + k];
        const float dbj = d[(be*15 + j)*15 + k];
        const float dbi = d[(be*15 + i)*15 + k];
        sre += faj*fbi + fai*fbj;
        sim += fai*dbj - faj*dbi;
      }
      wre = -4.f*DTC*sre;
      wim =  4.f*DTC*sim;
    } else {
      const int al = t - 225;
      wim = -4.f*DTC*f[(i*15 + al)*15 + j];
    }
    g_Wre[b*240 + t] = wre;
    g_Wim[b*240 + t] = wim;
  }

  if (t < 55) {
    if (t < 30) {
      const int a  = c_pa[t % 15], bb = c_pb[t % 15];
      const float* w4 = (t < 15) ? wx4 : wy4;
      const float* b4 = (t < 15) ? bx4 : by4;
      float s1 = 0.f, s2 = 0.f;
      for (int k = 0; k < 15; ++k) {
        const int oi = k*15 + i, oj = k*15 + j;
        const float Aia = (a  < 4) ? w4[oi*4 + a ] : b4[oi];
        const float Ajb = (bb < 4) ? w4[oj*4 + bb] : b4[oj];
        const float Aib = (bb < 4) ? w4[oi*4 + bb] : b4[oi];
        const float Aja = (a  < 4) ? w4[oj*4 + a ] : b4[oj];
        s1 += Aia*Ajb;
        s2 += Aib*Aja;
      }
      const float v = (a == bb) ? s1 : (s1 + s2);
      if (t < 15) g_Pxx[t*225 + b] = v;
      else        g_Pyy[(t-15)*225 + b] = v;
    } else {
      const int tt = t - 30, a = tt / 5, bb = tt % 5;
      float s = 0.f;
      for (int k = 0; k < 15; ++k) {
        const int oi = k*15 + i, oj = k*15 + j;
        const float Axia = (a  < 4) ? wx4[oi*4 + a ] : bx4[oi];
        const float Ayjb = (bb < 4) ? wy4[oj*4 + bb] : by4[oj];
        const float Ayib = (bb < 4) ? wy4[oi*4 + bb] : by4[oi];
        const float Axja = (a  < 4) ? wx4[oj*4 + a ] : bx4[oj];
        s += Axia*Ayjb - Ayib*Axja;
      }
      g_Cim[tt*225 + b] = s;
    }
  }
}

// ---------------------------------------------------------------------------
// PK2: assemble G[z][entry]; entry slot-swizzled
// ---------------------------------------------------------------------------
__global__ void pk2(const float* __restrict__ f, const float* __restrict__ omega)
{
  const int z = blockIdx.x;
  const int t = threadIdx.x;
  __shared__ float Prow[225];
  const float* W = nullptr; const float* P = nullptr;
  if (z < 15)      { P = g_Pxx + z*225;        W = g_Wre; }
  else if (z < 30) { P = g_Pyy + (z-15)*225;   W = g_Wre; }
  else if (z < 55) { P = g_Cim + (z-30)*225;   W = g_Wim; }
  if (P && t < 225) Prow[t] = P[t];
  __syncthreads();

  const int r = t >> 4, c = t & 15;
  float g = 0.f;
  if (P && r > 0) {
    const int de = (c >= 1) ? ((r-1)*15 + (c-1)) : (225 + (r-1));
    for (int ij = 0; ij < 225; ++ij)
      g = fmaf(W[ij*240 + de], Prow[ij], g);
    if (z == 14 && c >= 1) {
      float hc = 0.f;
      for (int k = 0; k < 15; ++k)
        hc = fmaf(f[((c-1)*15 + (r-1))*15 + k], omega[k], hc);
      g += DTC * 4.f * hc;
    }
  }
  const int c4 = c >> 2;
  const int slot = (c4 + (r >> 1)) & 3;
  g_G[(z << 8) + (r << 4) + (slot << 2) + (c & 3)] = g;
}

// ---------------------------------------------------------------------------
__device__ __forceinline__ void gemm_half(float (&acc)[4][16],
                                          const float* __restrict__ Gt,
                                          const float* __restrict__ Zl,
                                          int half, int w, int p, int q)
{
  #pragma unroll 2
  for (int zt = 0; zt < ZH; ++zt) {
    const float4 zv = *(const float4*)&Zl[(half*ZH + zt)*64 + (w << 4) + (p << 2)];
    const float za[4] = {zv.x, zv.y, zv.z, zv.w};
    #pragma unroll
    for (int lc = 0; lc < 4; ++lc) {
      const int slot = (lc + (q >> 1)) & 3;
      const float4 gv = *(const float4*)&Gt[(zt << 8) + (q << 4) + (slot << 2)];
      const float gg[4] = {gv.x, gv.y, gv.z, gv.w};
      #pragma unroll
      for (int jj = 0; jj < 4; ++jj)
        #pragma unroll
        for (int cc = 0; cc < 4; ++cc)
          acc[jj][(lc << 2) + cc] = fmaf(za[jj], gg[cc], acc[jj][(lc << 2) + cc]);
    }
  }
}

// C += P * Ms with B rows streamed from LDS at compile-time offsets.
// MUST be fully unrolled: any runtime index into P/C sends them to scratch.
__device__ __forceinline__ void mac16(float (&C)[4][16], const float (&P)[4][16],
                                      const float* __restrict__ Msamp)
{
  #pragma unroll
  for (int k2 = 0; k2 < 16; ++k2) {
    float bk[16];
    #pragma unroll
    for (int c4 = 0; c4 < 4; ++c4) {
      const float4 v = *(const float4*)&Msamp[k2*16 + (c4 << 2)];
      bk[(c4<<2)+0] = v.x; bk[(c4<<2)+1] = v.y;
      bk[(c4<<2)+2] = v.z; bk[(c4<<2)+3] = v.w;
    }
    #pragma unroll
    for (int u = 0; u < 4; ++u) {
      const float av = P[u][k2];
      #pragma unroll
      for (int c = 0; c < 16; ++c) C[u][c] = fmaf(av, bk[c], C[u][c]);
    }
  }
}

// ---------------------------------------------------------------------------
// main kernel: quad (4 lanes) per sample for expm; 64 samples/block/round.
// ---------------------------------------------------------------------------
__global__ void __launch_bounds__(256, 2)
mainker(const float* __restrict__ t_in, const float* __restrict__ x_in,
        const float* __restrict__ wx1, const float* __restrict__ bx1,
        const float* __restrict__ wx2, const float* __restrict__ bx2,
        const float* __restrict__ wx3, const float* __restrict__ bx3,
        const float* __restrict__ wy1, const float* __restrict__ by1,
        const float* __restrict__ wy2, const float* __restrict__ by2,
        const float* __restrict__ wy3, const float* __restrict__ by3,
        float* __restrict__ out, int B)
{
  __shared__ __align__(16) float S[64*SSTR];      // 66560 B (union)
  float* const Gt = S;                            // 7168 floats (GEMM phase)
  float* const Zl = S + ZH*256;                   // 3584 floats (GEMM phase)

  const int tid = threadIdx.x;
  const int w = tid >> 6;
  const int l = tid & 63;
  const int p = l & 3;
  const int q = l >> 2;

  for (int base = blockIdx.x*64; base < B; base += gridDim.x*64) {
    __syncthreads();                              // S free of prev-iter readers

    // ---- stage G half 0 ----
    #pragma unroll
    for (int ch = 0; ch < 7; ++ch) {
      const int off = (w*7 + ch)*256 + (l << 2);
      *(float4*)&Gt[off] = *(const float4*)&g_G[off];
    }
    // ---- Z (quad leads) ----
    if (p == 0) {
      const int zsmp = base + (w << 4) + q;
      const float tv = (zsmp < B) ? t_in[zsmp] : 0.f;
      float hx[5], hy[5];
      {
        const float a0 = fmaxf(fmaf(wx1[0], tv, bx1[0]), 0.f);
        const float a1 = fmaxf(fmaf(wx1[1], tv, bx1[1]), 0.f);
        float h2[4];
        #pragma unroll
        for (int o = 0; o < 4; ++o)
          h2[o] = fmaxf(wx2[o*2+0]*a0 + wx2[o*2+1]*a1 + bx2[o], 0.f);
        #pragma unroll
        for (int o = 0; o < 4; ++o)
          hx[o] = fmaxf(wx3[o*4+0]*h2[0] + wx3[o*4+1]*h2[1] +
                        wx3[o*4+2]*h2[2] + wx3[o*4+3]*h2[3] + bx3[o], 0.f);
        hx[4] = 1.f;
      }
      {
        const float a0 = fmaxf(fmaf(wy1[0], tv, by1[0]), 0.f);
        const float a1 = fmaxf(fmaf(wy1[1], tv, by1[1]), 0.f);
        float h2[4];
        #pragma unroll
        for (int o = 0; o < 4; ++o)
          h2[o] = fmaxf(wy2[o*2+0]*a0 + wy2[o*2+1]*a1 + by2[o], 0.f);
        #pragma unroll
        for (int o = 0; o < 4; ++o)
          hy[o] = fmaxf(wy3[o*4+0]*h2[0] + wy3[o*4+1]*h2[1] +
                        wy3[o*4+2]*h2[2] + wy3[o*4+3]*h2[3] + by3[o], 0.f);
        hy[4] = 1.f;
      }
      const int col = (w << 4) + q;
      constexpr int zb[5] = {0,5,9,12,14};
      #pragma unroll
      for (int a = 0; a < 5; ++a)
        #pragma unroll
        for (int b2 = a; b2 < 5; ++b2) {
          Zl[(zb[a] + b2 - a)*64 + col]      = hx[a]*hx[b2];
          Zl[(15 + zb[a] + b2 - a)*64 + col] = hy[a]*hy[b2];
        }
      #pragma unroll
      for (int a = 0; a < 5; ++a)
        #pragma unroll
        for (int b2 = 0; b2 < 5; ++b2)
          Zl[(30 + a*5 + b2)*64 + col] = hx[a]*hy[b2];
      Zl[55*64 + col] = 0.f;
    }
    __syncthreads();

    // ---- GEMM: lane (w,q,p) computes row q of samples base+w*16+p*4+{0..3}
    float acc[4][16];
    #pragma unroll
    for (int jj = 0; jj < 4; ++jj)
      #pragma unroll
      for (int cc = 0; cc < 16; ++cc) acc[jj][cc] = 0.f;

    gemm_half(acc, Gt, Zl, 0, w, p, q);
    __syncthreads();
    #pragma unroll
    for (int ch = 0; ch < 7; ++ch) {
      const int off = (w*7 + ch)*256 + (l << 2);
      *(float4*)&Gt[off] = *(const float4*)&g_G[ZH*256 + off];
    }
    __syncthreads();
    gemm_half(acc, Gt, Zl, 1, w, p, q);
    __syncthreads();                              // Gt/Zl reads done

    // ---- write M rows straight into per-sample LDS slots ----
    {
      float* Ms0 = S + (w*16 + p*4)*SSTR + q*16;
      #pragma unroll
      for (int jj = 0; jj < 4; ++jj)
        #pragma unroll
        for (int c4 = 0; c4 < 4; ++c4)
          *(float4*)&Ms0[jj*SSTR + (c4 << 2)] =
            make_float4(acc[jj][(c4<<2)+0], acc[jj][(c4<<2)+1],
                        acc[jj][(c4<<2)+2], acc[jj][(c4<<2)+3]);
    }
    __syncthreads();

    // ---- expm on quad's sample ----
    const int smp = base + (w << 4) + q;
    float* const Msamp = S + ((w << 4) + q)*SSTR;

    // own 4 rows -> norm -> scale -> write back scaled
    float Mo[4][16];
    #pragma unroll
    for (int u = 0; u < 4; ++u)
      #pragma unroll
      for (int c4 = 0; c4 < 4; ++c4) {
        const float4 v = *(const float4*)&Msamp[(p*4 + u)*16 + (c4 << 2)];
        Mo[u][(c4<<2)+0] = v.x; Mo[u][(c4<<2)+1] = v.y;
        Mo[u][(c4<<2)+2] = v.z; Mo[u][(c4<<2)+3] = v.w;
      }
    float nrm = 0.f;
    #pragma unroll
    for (int u = 0; u < 4; ++u) {
      float rs = 0.f;
      #pragma unroll
      for (int c = 0; c < 16; ++c) rs += fabsf(Mo[u][c]);
      nrm = fmaxf(nrm, rs);
    }
    nrm = fmaxf(nrm, QPERM(0xB1, nrm));
    nrm = fmaxf(nrm, QPERM(0x4E, nrm));
    // scale so ||M/2^sq||_inf <= 0.5 ; Taylor-6 error ~ 0.5^7/5040 = 1.5e-6
    int sq = 0;
    if (nrm > 0.5f) sq = (int)ceilf(log2f(nrm * 2.f));
    sq = (sq < 0) ? 0 : ((sq > 40) ? 40 : sq);
    const float sc = exp2f((float)(-sq));
    #pragma unroll
    for (int u = 0; u < 4; ++u)
      #pragma unroll
      for (int c = 0; c < 16; ++c) Mo[u][c] *= sc;
    #pragma unroll
    for (int u = 0; u < 4; ++u)
      #pragma unroll
      for (int c4 = 0; c4 < 4; ++c4)
        *(float4*)&Msamp[(p*4 + u)*16 + (c4 << 2)] =
          make_float4(Mo[u][(c4<<2)+0], Mo[u][(c4<<2)+1],
                      Mo[u][(c4<<2)+2], Mo[u][(c4<<2)+3]);
    asm volatile("s_waitcnt lgkmcnt(0)" ::: "memory");

    // Horner Taylor-6: P = Ms/6; then 5x: P = (P + I)*Ms/k, k=5..1
    float P[4][16];
    #pragma unroll
    for (int u = 0; u < 4; ++u)
      #pragma unroll
      for (int c = 0; c < 16; ++c) P[u][c] = Mo[u][c] * (1.f/6.f);

    #pragma unroll 1
    for (int s7 = 0; s7 < 5; ++s7) {
      float C[4][16];
      #pragma unroll
      for (int u = 0; u < 4; ++u)                 // C = Ms (the +I*Ms term)
        #pragma unroll
        for (int c4 = 0; c4 < 4; ++c4) {
          const float4 v = *(const float4*)&Msamp[(p*4 + u)*16 + (c4 << 2)];
          C[u][(c4<<2)+0] = v.x; C[u][(c4<<2)+1] = v.y;
          C[u][(c4<<2)+2] = v.z; C[u][(c4<<2)+3] = v.w;
        }
      mac16(C, P, Msamp);                         // C += P*Ms (fully unrolled)
      const float ik = 1.f / (float)(5 - s7);     // no runtime-indexed table
      #pragma unroll
      for (int u = 0; u < 4; ++u)
        #pragma unroll
        for (int c = 0; c < 16; ++c) P[u][c] = C[u][c] * ik;
    }
    // E = I + P

    // squaring: P <- P^2 + 2P  (B = P from LDS, rewritten per iter)
    #pragma unroll 1
    for (int it2 = 0; it2 < sq; ++it2) {
      #pragma unroll
      for (int u = 0; u < 4; ++u)
        #pragma unroll
        for (int c4 = 0; c4 < 4; ++c4)
          *(float4*)&Msamp[(p*4 + u)*16 + (c4 << 2)] =
            make_float4(P[u][(c4<<2)+0], P[u][(c4<<2)+1],
                        P[u][(c4<<2)+2], P[u][(c4<<2)+3]);
      asm volatile("s_waitcnt lgkmcnt(0)" ::: "memory");
      float C[4][16];
      #pragma unroll
      for (int u = 0; u < 4; ++u)
        #pragma unroll
        for (int c = 0; c < 16; ++c) C[u][c] = 2.f*P[u][c];
      mac16(C, P, Msamp);
      #pragma unroll
      for (int u = 0; u < 4; ++u)
        #pragma unroll
        for (int c = 0; c < 16; ++c) P[u][c] = C[u][c];
    }

    // ---- output: out[j] = P[row][0] + sum_i x_i P[row][i+1] + x[row-1] ----
    if (smp < B) {
      float xv[15];
      #pragma unroll
      for (int i2 = 0; i2 < 15; ++i2) xv[i2] = x_in[smp*15 + i2];
      #pragma unroll
      for (int u = 0; u < 4; ++u) {
        const int row = (p << 2) + u;
        if (row >= 1) {
          float o = P[u][0];
          #pragma unroll
          for (int i2 = 0; i2 < 15; ++i2) o = fmaf(xv[i2], P[u][1 + i2], o);
          o += xv[row - 1];
          out[smp*15 + (row - 1)] = o;
        }
      }
    }
  }
}

// ---------------------------------------------------------------------------
extern "C" void kernel_launch(void* const* d_in, const int* in_sizes, int n_in,
                              void* d_out, int out_size, void* d_ws, size_t ws_size,
                              hipStream_t stream)
{
  const float* t   = (const float*)d_in[0];
  const float* x   = (const float*)d_in[1];
  const float* om  = (const float*)d_in[2];
  const float* f   = (const float*)d_in[3];
  const float* dd  = (const float*)d_in[4];
  const float* wx1 = (const float*)d_in[5];  const float* bx1 = (const float*)d_in[6];
  const float* wx2 = (const float*)d_in[7];  const float* bx2 = (const float*)d_in[8];
  const float* wx3 = (const float*)d_in[9];  const float* bx3 = (const float*)d_in[10];
  const float* wx4 = (const float*)d_in[11]; const float* bx4 = (const float*)d_in[12];
  const float* wy1 = (const float*)d_in[13]; const float* by1 = (const float*)d_in[14];
  const float* wy2 = (const float*)d_in[15]; const float* by2 = (const float*)d_in[16];
  const float* wy3 = (const float*)d_in[17]; const float* by3 = (const float*)d_in[18];
  const float* wy4 = (const float*)d_in[19]; const float* by4 = (const float*)d_in[20];
  float* out = (float*)d_out;
  const int B = in_sizes[0];

  hipLaunchKernelGGL(pk1, dim3(225), dim3(256), 0, stream, f, dd, wx4, bx4, wy4, by4);
  hipLaunchKernelGGL(pk2, dim3(56),  dim3(256), 0, stream, f, om);
  hipLaunchKernelGGL(mainker, dim3(1024), dim3(256), 0, stream,
                     t, x, wx1, bx1, wx2, bx2, wx3, bx3,
                     wy1, by1, wy2, by2, wy3, by3, out, B);
}

// Round 10
// 244.221 us; speedup vs baseline: 1.9377x; 1.9377x over previous
//
#include <hip/hip_runtime.h>
#include <math.h>

#define DTC 0.01f
#define NZ 56      // 55 Z components + 1 zero pad
#define ZH 28      // z per staged half-tile
#define SSTR 260   // per-sample M stride in floats (256 + 4 pad for banks)

// ---------------- device scratch ----------------
__device__ float g_Wre[225*240];   // [ij][de]
__device__ float g_Wim[225*240];
__device__ float g_Pxx[15*225];
__device__ float g_Pyy[15*225];
__device__ float g_Cim[25*225];
__device__ float g_G  [NZ*256];    // [z][entry], entry slot-swizzled

__constant__ int c_pa[15] = {0,0,0,0,0,1,1,1,1,2,2,2,3,3,4};
__constant__ int c_pb[15] = {0,1,2,3,4,1,2,3,4,2,3,4,3,4,4};

#define QPERM(ctrl_, v_) __int_as_float(__builtin_amdgcn_update_dpp( \
    __float_as_int(v_), __float_as_int(v_), (ctrl_), 0xF, 0xF, true))

// ---------------------------------------------------------------------------
// PK1: per (i,j) block: W rows (structure-constant contractions) + P tensors
// ---------------------------------------------------------------------------
__global__ void pk1(const float* __restrict__ f, const float* __restrict__ d,
                    const float* __restrict__ wx4, const float* __restrict__ bx4,
                    const float* __restrict__ wy4, const float* __restrict__ by4)
{
  const int b = blockIdx.x;           // ij = i*15+j
  const int i = b / 15, j = b % 15;
  const int t = threadIdx.x;

  if (t < 240) {
    float wre = 0.f, wim = 0.f;
    if (t < 225) {
      const int al = t / 15, be = t % 15;
      float sre = 0.f, sim = 0.f;
      for (int k = 0; k < 15; ++k) {
        const float faj = f[(al*15 + j)*15 + k];
        const float fai = f[(al*15 + i)*15 + k];
        const float fbi = f[(be*15 + i)*15 + k];
        const float fbj = f[(be*15 + j)*15 + k];
        const float dbj = d[(be*15 + j)*15 + k];
        const float dbi = d[(be*15 + i)*15 + k];
        sre += faj*fbi + fai*fbj;
        sim += fai*dbj - faj*dbi;
      }
      wre = -4.f*DTC*sre;
      wim =  4.f*DTC*sim;
    } else {
      const int al = t - 225;
      wim = -4.f*DTC*f[(i*15 + al)*15 + j];
    }
    g_Wre[b*240 + t] = wre;
    g_Wim[b*240 + t] = wim;
  }

  if (t < 55) {
    if (t < 30) {
      const int a  = c_pa[t % 15], bb = c_pb[t % 15];
      const float* w4 = (t < 15) ? wx4 : wy4;
      const float* b4 = (t < 15) ? bx4 : by4;
      float s1 = 0.f, s2 = 0.f;
      for (int k = 0; k < 15; ++k) {
        const int oi = k*15 + i, oj = k*15 + j;
        const float Aia = (a  < 4) ? w4[oi*4 + a ] : b4[oi];
        const float Ajb = (bb < 4) ? w4[oj*4 + bb] : b4[oj];
        const float Aib = (bb < 4) ? w4[oi*4 + bb] : b4[oi];
        const float Aja = (a  < 4) ? w4[oj*4 + a ] : b4[oj];
        s1 += Aia*Ajb;
        s2 += Aib*Aja;
      }
      const float v = (a == bb) ? s1 : (s1 + s2);
      if (t < 15) g_Pxx[t*225 + b] = v;
      else        g_Pyy[(t-15)*225 + b] = v;
    } else {
      const int tt = t - 30, a = tt / 5, bb = tt % 5;
      float s = 0.f;
      for (int k = 0; k < 15; ++k) {
        const int oi = k*15 + i, oj = k*15 + j;
        const float Axia = (a  < 4) ? wx4[oi*4 + a ] : bx4[oi];
        const float Ayjb = (bb < 4) ? wy4[oj*4 + bb] : by4[oj];
        const float Ayib = (bb < 4) ? wy4[oi*4 + bb] : by4[oi];
        const float Axja = (a  < 4) ? wx4[oj*4 + a ] : bx4[oj];
        s += Axia*Ayjb - Ayib*Axja;
      }
      g_Cim[tt*225 + b] = s;
    }
  }
}

// ---------------------------------------------------------------------------
// PK2: assemble G[z][entry]; entry slot-swizzled
// ---------------------------------------------------------------------------
__global__ void pk2(const float* __restrict__ f, const float* __restrict__ omega)
{
  const int z = blockIdx.x;
  const int t = threadIdx.x;
  __shared__ float Prow[225];
  const float* W = nullptr; const float* P = nullptr;
  if (z < 15)      { P = g_Pxx + z*225;        W = g_Wre; }
  else if (z < 30) { P = g_Pyy + (z-15)*225;   W = g_Wre; }
  else if (z < 55) { P = g_Cim + (z-30)*225;   W = g_Wim; }
  if (P && t < 225) Prow[t] = P[t];
  __syncthreads();

  const int r = t >> 4, c = t & 15;
  float g = 0.f;
  if (P && r > 0) {
    const int de = (c >= 1) ? ((r-1)*15 + (c-1)) : (225 + (r-1));
    for (int ij = 0; ij < 225; ++ij)
      g = fmaf(W[ij*240 + de], Prow[ij], g);
    if (z == 14 && c >= 1) {
      float hc = 0.f;
      for (int k = 0; k < 15; ++k)
        hc = fmaf(f[((c-1)*15 + (r-1))*15 + k], omega[k], hc);
      g += DTC * 4.f * hc;
    }
  }
  const int c4 = c >> 2;
  const int slot = (c4 + (r >> 1)) & 3;
  g_G[(z << 8) + (r << 4) + (slot << 2) + (c & 3)] = g;
}

// ---------------------------------------------------------------------------
__device__ __forceinline__ void gemm_half(float (&acc)[4][16],
                                          const float* __restrict__ Gt,
                                          const float* __restrict__ Zl,
                                          int half, int w, int p, int q)
{
  #pragma unroll 2
  for (int zt = 0; zt < ZH; ++zt) {
    const float4 zv = *(const float4*)&Zl[(half*ZH + zt)*64 + (w << 4) + (p << 2)];
    const float za[4] = {zv.x, zv.y, zv.z, zv.w};
    #pragma unroll
    for (int lc = 0; lc < 4; ++lc) {
      const int slot = (lc + (q >> 1)) & 3;
      const float4 gv = *(const float4*)&Gt[(zt << 8) + (q << 4) + (slot << 2)];
      const float gg[4] = {gv.x, gv.y, gv.z, gv.w};
      #pragma unroll
      for (int jj = 0; jj < 4; ++jj)
        #pragma unroll
        for (int cc = 0; cc < 4; ++cc)
          acc[jj][(lc << 2) + cc] = fmaf(za[jj], gg[cc], acc[jj][(lc << 2) + cc]);
    }
  }
}

// C2 += A2 * B2 for 16x16 distributed 4 rows/lane in a quad (row 4p+u on lane
// p). B row 0 assumed zero (true: M row 0 = 0, preserved by all powers).
// C2 must be pre-initialized by the caller (Mo for Horner, 2P for squaring).
// All indices compile-time; B broadcast via DPP quad_perm — zero LDS.
__device__ __forceinline__ void mm16q(float (&C2)[4][16],
                                      const float (&A2)[4][16],
                                      const float (&B2)[4][16])
{
#define KSTEP(kk) { \
    float bk[16]; \
    _Pragma("unroll") \
    for (int c = 0; c < 16; ++c) bk[c] = QPERM((((kk) >> 2) * 0x55), B2[(kk) & 3][c]); \
    _Pragma("unroll") \
    for (int u = 0; u < 4; ++u) { \
      const float av = A2[u][kk]; \
      _Pragma("unroll") \
      for (int c = 0; c < 16; ++c) C2[u][c] = fmaf(av, bk[c], C2[u][c]); \
    } }
  KSTEP(1) KSTEP(2) KSTEP(3) KSTEP(4) KSTEP(5) KSTEP(6) KSTEP(7) KSTEP(8)
  KSTEP(9) KSTEP(10) KSTEP(11) KSTEP(12) KSTEP(13) KSTEP(14) KSTEP(15)
#undef KSTEP
}

// ---------------------------------------------------------------------------
// main kernel: quad (4 lanes) per sample for expm; 64 samples/block/round.
// expm is fully register-resident (Mo, P, C distributed 4 rows/lane);
// amdgpu_waves_per_eu(2,2) grants the 256-VGPR budget (occupancy is
// LDS-capped at 2 blocks/CU anyway), eliminating the R2/R3 scratch spills.
// ---------------------------------------------------------------------------
__attribute__((amdgpu_waves_per_eu(2, 2)))
__global__ void __launch_bounds__(256)
mainker(const float* __restrict__ t_in, const float* __restrict__ x_in,
        const float* __restrict__ wx1, const float* __restrict__ bx1,
        const float* __restrict__ wx2, const float* __restrict__ bx2,
        const float* __restrict__ wx3, const float* __restrict__ bx3,
        const float* __restrict__ wy1, const float* __restrict__ by1,
        const float* __restrict__ wy2, const float* __restrict__ by2,
        const float* __restrict__ wy3, const float* __restrict__ by3,
        float* __restrict__ out, int B)
{
  __shared__ __align__(16) float S[64*SSTR];      // 66560 B (union)
  float* const Gt = S;                            // 7168 floats (GEMM phase)
  float* const Zl = S + ZH*256;                   // 3584 floats (GEMM phase)

  const int tid = threadIdx.x;
  const int w = tid >> 6;
  const int l = tid & 63;
  const int p = l & 3;
  const int q = l >> 2;

  for (int base = blockIdx.x*64; base < B; base += gridDim.x*64) {
    __syncthreads();                              // S free of prev-iter readers

    // ---- stage G half 0 ----
    #pragma unroll
    for (int ch = 0; ch < 7; ++ch) {
      const int off = (w*7 + ch)*256 + (l << 2);
      *(float4*)&Gt[off] = *(const float4*)&g_G[off];
    }
    // ---- Z (quad leads) ----
    if (p == 0) {
      const int zsmp = base + (w << 4) + q;
      const float tv = (zsmp < B) ? t_in[zsmp] : 0.f;
      float hx[5], hy[5];
      {
        const float a0 = fmaxf(fmaf(wx1[0], tv, bx1[0]), 0.f);
        const float a1 = fmaxf(fmaf(wx1[1], tv, bx1[1]), 0.f);
        float h2[4];
        #pragma unroll
        for (int o = 0; o < 4; ++o)
          h2[o] = fmaxf(wx2[o*2+0]*a0 + wx2[o*2+1]*a1 + bx2[o], 0.f);
        #pragma unroll
        for (int o = 0; o < 4; ++o)
          hx[o] = fmaxf(wx3[o*4+0]*h2[0] + wx3[o*4+1]*h2[1] +
                        wx3[o*4+2]*h2[2] + wx3[o*4+3]*h2[3] + bx3[o], 0.f);
        hx[4] = 1.f;
      }
      {
        const float a0 = fmaxf(fmaf(wy1[0], tv, by1[0]), 0.f);
        const float a1 = fmaxf(fmaf(wy1[1], tv, by1[1]), 0.f);
        float h2[4];
        #pragma unroll
        for (int o = 0; o < 4; ++o)
          h2[o] = fmaxf(wy2[o*2+0]*a0 + wy2[o*2+1]*a1 + by2[o], 0.f);
        #pragma unroll
        for (int o = 0; o < 4; ++o)
          hy[o] = fmaxf(wy3[o*4+0]*h2[0] + wy3[o*4+1]*h2[1] +
                        wy3[o*4+2]*h2[2] + wy3[o*4+3]*h2[3] + by3[o], 0.f);
        hy[4] = 1.f;
      }
      const int col = (w << 4) + q;
      constexpr int zb[5] = {0,5,9,12,14};
      #pragma unroll
      for (int a = 0; a < 5; ++a)
        #pragma unroll
        for (int b2 = a; b2 < 5; ++b2) {
          Zl[(zb[a] + b2 - a)*64 + col]      = hx[a]*hx[b2];
          Zl[(15 + zb[a] + b2 - a)*64 + col] = hy[a]*hy[b2];
        }
      #pragma unroll
      for (int a = 0; a < 5; ++a)
        #pragma unroll
        for (int b2 = 0; b2 < 5; ++b2)
          Zl[(30 + a*5 + b2)*64 + col] = hx[a]*hy[b2];
      Zl[55*64 + col] = 0.f;
    }
    __syncthreads();

    // ---- GEMM: lane (w,q,p) computes row q of samples base+w*16+p*4+{0..3}
    float acc[4][16];
    #pragma unroll
    for (int jj = 0; jj < 4; ++jj)
      #pragma unroll
      for (int cc = 0; cc < 16; ++cc) acc[jj][cc] = 0.f;

    gemm_half(acc, Gt, Zl, 0, w, p, q);
    __syncthreads();
    #pragma unroll
    for (int ch = 0; ch < 7; ++ch) {
      const int off = (w*7 + ch)*256 + (l << 2);
      *(float4*)&Gt[off] = *(const float4*)&g_G[ZH*256 + off];
    }
    __syncthreads();
    gemm_half(acc, Gt, Zl, 1, w, p, q);
    __syncthreads();                              // Gt/Zl reads done

    // ---- write M rows into per-sample LDS slots (reshuffle only) ----
    {
      float* Ms0 = S + (w*16 + p*4)*SSTR + q*16;
      #pragma unroll
      for (int jj = 0; jj < 4; ++jj)
        #pragma unroll
        for (int c4 = 0; c4 < 4; ++c4)
          *(float4*)&Ms0[jj*SSTR + (c4 << 2)] =
            make_float4(acc[jj][(c4<<2)+0], acc[jj][(c4<<2)+1],
                        acc[jj][(c4<<2)+2], acc[jj][(c4<<2)+3]);
    }
    __syncthreads();

    // ---- expm on quad's sample: all register-resident from here ----
    const int smp = base + (w << 4) + q;
    const float* const Msamp = S + ((w << 4) + q)*SSTR;

    float Mo[4][16];                              // rows 4p+u of this sample
    #pragma unroll
    for (int u = 0; u < 4; ++u)
      #pragma unroll
      for (int c4 = 0; c4 < 4; ++c4) {
        const float4 v = *(const float4*)&Msamp[(p*4 + u)*16 + (c4 << 2)];
        Mo[u][(c4<<2)+0] = v.x; Mo[u][(c4<<2)+1] = v.y;
        Mo[u][(c4<<2)+2] = v.z; Mo[u][(c4<<2)+3] = v.w;
      }

    float nrm = 0.f;
    #pragma unroll
    for (int u = 0; u < 4; ++u) {
      float rs = 0.f;
      #pragma unroll
      for (int c = 0; c < 16; ++c) rs += fabsf(Mo[u][c]);
      nrm = fmaxf(nrm, rs);
    }
    nrm = fmaxf(nrm, QPERM(0xB1, nrm));
    nrm = fmaxf(nrm, QPERM(0x4E, nrm));
    // scale so ||M/2^sq||_inf <= 0.5 ; Taylor-6 error ~ 0.5^7/5040 = 1.5e-6
    int sq = 0;
    if (nrm > 0.5f) sq = (int)ceilf(log2f(nrm * 2.f));
    sq = (sq < 0) ? 0 : ((sq > 40) ? 40 : sq);
    const float sc = exp2f((float)(-sq));
    #pragma unroll
    for (int u = 0; u < 4; ++u)
      #pragma unroll
      for (int c = 0; c < 16; ++c) Mo[u][c] *= sc;

    // Horner Taylor-6: P = Mo/6; then 5x: P = (I + P)*Mo / k, k=5..1
    float P[4][16];
    #pragma unroll
    for (int u = 0; u < 4; ++u)
      #pragma unroll
      for (int c = 0; c < 16; ++c) P[u][c] = Mo[u][c] * (1.f/6.f);

    #pragma unroll 1
    for (int s7 = 0; s7 < 5; ++s7) {
      float C[4][16];
      #pragma unroll
      for (int u = 0; u < 4; ++u)                 // C = Mo (the I*Mo term)
        #pragma unroll
        for (int c = 0; c < 16; ++c) C[u][c] = Mo[u][c];
      mm16q(C, P, Mo);                            // C += P*Mo
      const float ik = 1.f / (float)(5 - s7);
      #pragma unroll
      for (int u = 0; u < 4; ++u)
        #pragma unroll
        for (int c = 0; c < 16; ++c) P[u][c] = C[u][c] * ik;
    }
    // E = I + P

    // squaring: P <- P^2 + 2P (all registers; P row 0 stays zero)
    #pragma unroll 1
    for (int it2 = 0; it2 < sq; ++it2) {
      float C[4][16];
      #pragma unroll
      for (int u = 0; u < 4; ++u)
        #pragma unroll
        for (int c = 0; c < 16; ++c) C[u][c] = 2.f*P[u][c];
      mm16q(C, P, P);
      #pragma unroll
      for (int u = 0; u < 4; ++u)
        #pragma unroll
        for (int c = 0; c < 16; ++c) P[u][c] = C[u][c];
    }

    // ---- output: out[j] = P[row][0] + sum_i x_i P[row][i+1] + x[row-1] ----
    if (smp < B) {
      float xv[15];
      #pragma unroll
      for (int i2 = 0; i2 < 15; ++i2) xv[i2] = x_in[smp*15 + i2];
      #pragma unroll
      for (int u = 0; u < 4; ++u) {
        const int row = (p << 2) + u;
        if (row >= 1) {
          float o = P[u][0];
          #pragma unroll
          for (int i2 = 0; i2 < 15; ++i2) o = fmaf(xv[i2], P[u][1 + i2], o);
          o += xv[row - 1];
          out[smp*15 + (row - 1)] = o;
        }
      }
    }
  }
}

// ---------------------------------------------------------------------------
extern "C" void kernel_launch(void* const* d_in, const int* in_sizes, int n_in,
                              void* d_out, int out_size, void* d_ws, size_t ws_size,
                              hipStream_t stream)
{
  const float* t   = (const float*)d_in[0];
  const float* x   = (const float*)d_in[1];
  const float* om  = (const float*)d_in[2];
  const float* f   = (const float*)d_in[3];
  const float* dd  = (const float*)d_in[4];
  const float* wx1 = (const float*)d_in[5];  const float* bx1 = (const float*)d_in[6];
  const float* wx2 = (const float*)d_in[7];  const float* bx2 = (const float*)d_in[8];
  const float* wx3 = (const float*)d_in[9];  const float* bx3 = (const float*)d_in[10];
  const float* wx4 = (const float*)d_in[11]; const float* bx4 = (const float*)d_in[12];
  const float* wy1 = (const float*)d_in[13]; const float* by1 = (const float*)d_in[14];
  const float* wy2 = (const float*)d_in[15]; const float* by2 = (const float*)d_in[16];
  const float* wy3 = (const float*)d_in[17]; const float* by3 = (const float*)d_in[18];
  const float* wy4 = (const float*)d_in[19]; const float* by4 = (const float*)d_in[20];
  float* out = (float*)d_out;
  const int B = in_sizes[0];

  hipLaunchKernelGGL(pk1, dim3(225), dim3(256), 0, stream, f, dd, wx4, bx4, wy4, by4);
  hipLaunchKernelGGL(pk2, dim3(56),  dim3(256), 0, stream, f, om);
  hipLaunchKernelGGL(mainker, dim3(1024), dim3(256), 0, stream,
                     t, x, wx1, bx1, wx2, bx2, wx3, bx3,
                     wy1, by1, wy2, by2, wy3, by3, out, B);
}